// Round 5
// baseline (751.164 us; speedup 1.0000x reference)
//
#include <hip/hip_runtime.h>

// GNetFVnewGCN: x[N,127], node_attr[N,1], edge_index[2,E] (int32), edge_attr[E,6],
// W_in[6,256], b_in[256], W_out[256,128], b_out[128] -> out[N,128] fp32
//
// R5: dispatch-count reduction (9 -> 5+memset) + aggregate tail-split.
//   D0 memset(counts+done)
//   D1 hist_scan   : histogram of dst + last-block-done in-kernel exclusive scan
//   D2 scatter_concat: payload scatter (srcs+eas) || xc concat, one launch
//   D3 aggregate8b : atomic-free wave/node aggregation, 8/4/1 tail-split
//   D4 node_kernel2: fp32 GEMM [N,256]@[256,128] + tanh
// Tiers: A (payload ~199MB) -> B (perm path ~117MB) -> C (atomic).

#define ATTR 6

// ---------------- D1: hist + in-kernel scan ----------------

__global__ __launch_bounds__(256) void hist_scan_kernel(
    const int* __restrict__ ei, int* __restrict__ counts, int* __restrict__ done,
    int* __restrict__ offsets, int* __restrict__ cursors, int E, int N)
{
  const int t = threadIdx.x;
  // --- hist phase: 4 edges per thread, vectorized dst load when aligned ---
  const int e0 = blockIdx.x * 1024 + t * 4;
  if (((E & 3) == 0) && (e0 + 4 <= E)) {
    const int4 d = *(const int4*)(ei + E + e0);
    atomicAdd(&counts[d.x], 1);
    atomicAdd(&counts[d.y], 1);
    atomicAdd(&counts[d.z], 1);
    atomicAdd(&counts[d.w], 1);
  } else {
#pragma unroll
    for (int j = 0; j < 4; ++j) {
      const int e = e0 + j;
      if (e < E) atomicAdd(&counts[ei[E + e]], 1);
    }
  }

  // --- last-block-done: the final block performs the scan ---
  __threadfence();
  __syncthreads();
  __shared__ int lastFlag;
  if (t == 0) lastFlag = (atomicAdd(done, 1) == (int)gridDim.x - 1) ? 1 : 0;
  __syncthreads();
  if (!lastFlag) return;
  __threadfence();

  const int lane = t & 63;
  const int w = t >> 6;
  __shared__ int wsum[4];
  int rbase = 0;
  const int ntiles = (N + 4095) >> 12;
  for (int tile = 0; tile < ntiles; ++tile) {
    const int i0 = (tile << 12) + t * 16;
    int c[16]; int s = 0;
#pragma unroll
    for (int j = 0; j < 16; ++j) {
      const int i = i0 + j;
      c[j] = (i < N) ? __hip_atomic_load(&counts[i], __ATOMIC_RELAXED,
                                         __HIP_MEMORY_SCOPE_AGENT) : 0;
      s += c[j];
    }
    int sc = s;                      // wave-inclusive scan of per-thread sums
#pragma unroll
    for (int d = 1; d < 64; d <<= 1) {
      const int u = __shfl_up(sc, d, 64);
      if (lane >= d) sc += u;
    }
    if (lane == 63) wsum[w] = sc;
    __syncthreads();
    int wpre = 0;
#pragma unroll
    for (int k = 0; k < 4; ++k) if (k < w) wpre += wsum[k];
    const int tot = wsum[0] + wsum[1] + wsum[2] + wsum[3];
    int excl = rbase + wpre + (sc - s);
#pragma unroll
    for (int j = 0; j < 16; ++j) {
      const int i = i0 + j;
      if (i < N) { offsets[i] = excl; cursors[i] = excl; }
      excl += c[j];
    }
    rbase += tot;
    __syncthreads();
  }
  if (t == 0) offsets[N] = E;
}

// ---------------- D2: payload scatter || concat, fused ----------------

__global__ __launch_bounds__(256) void scatter_concat_kernel(
    const int* __restrict__ ei, const float* __restrict__ ea,
    int* __restrict__ cursors, int* __restrict__ srcs, float* __restrict__ eas,
    const float* __restrict__ x, const float* __restrict__ na,
    float* __restrict__ xc, int E, int N, int SB)
{
  if ((int)blockIdx.x < SB) {
    const int e = blockIdx.x * 256 + threadIdx.x;
    if (e < E) {
      const int dst = ei[E + e];
      const int slot = atomicAdd(&cursors[dst], 1);
      srcs[slot] = ei[e];
      const float2 a0 = *(const float2*)(ea + (size_t)e * ATTR + 0);
      const float2 a1 = *(const float2*)(ea + (size_t)e * ATTR + 2);
      const float2 a2 = *(const float2*)(ea + (size_t)e * ATTR + 4);
      float* ep = eas + (size_t)slot * ATTR;
      *(float2*)(ep + 0) = a0;
      *(float2*)(ep + 2) = a1;
      *(float2*)(ep + 4) = a2;
    }
  } else {
    const int gid = (blockIdx.x - SB) * 256 + threadIdx.x;  // thread per float4
    const int row = gid >> 5;
    const int c4 = (gid & 31) * 4;
    if (row < N) {
      const float* xr = x + (size_t)row * 127;
      float4 v;
      v.x = xr[c4];
      v.y = xr[c4 + 1];
      v.z = xr[c4 + 2];
      v.w = (c4 == 124) ? na[row] : xr[c4 + 3];
      *(float4*)(xc + (size_t)row * 128 + c4) = v;
    }
  }
}

// ---------------- D3: aggregation, wave/node, 8/4/1 tail-split ----------------

__global__ __launch_bounds__(256) void aggregate8b_kernel(
    const float* __restrict__ xc,
    const float* __restrict__ W_in, const float* __restrict__ b_in,
    const int* __restrict__ offsets, const int* __restrict__ srcs,
    const float* __restrict__ eas,
    float* __restrict__ aggr, int N)
{
  const int L = threadIdx.x & 63;
  const int n = __builtin_amdgcn_readfirstlane(blockIdx.x * 4 + (threadIdx.x >> 6));
  if (n >= N) return;

  // lane L owns channels c_lo=L (k=2L,2L+1) and c_hi=64+L (k=128+2L,129+2L)
  float2 wlo[ATTR], whi[ATTR];
#pragma unroll
  for (int a = 0; a < ATTR; ++a) {
    wlo[a] = *(const float2*)(W_in + a * 256 + 2 * L);
    whi[a] = *(const float2*)(W_in + a * 256 + 128 + 2 * L);
  }
  const float2 blo = *(const float2*)(b_in + 2 * L);
  const float2 bhi = *(const float2*)(b_in + 128 + 2 * L);

  float alo0 = 0.f, alo1 = 0.f, ahi0 = 0.f, ahi1 = 0.f;
  const int beg = __builtin_amdgcn_readfirstlane(offsets[n]);
  const int end = __builtin_amdgcn_readfirstlane(offsets[n + 1]);

  int i0 = beg;
  // ---- full groups of 8, no clamps ----
  for (; i0 + 8 <= end; i0 += 8) {
    int s8[8];
#pragma unroll
    for (int j = 0; j < 8; ++j) s8[j] = srcs[i0 + j];
    float eav[8][ATTR];
#pragma unroll
    for (int j = 0; j < 8; ++j)
#pragma unroll
      for (int a = 0; a < ATTR; ++a) eav[j][a] = eas[(size_t)(i0 + j) * ATTR + a];

    float xlo[8], xhi[8];
#pragma unroll
    for (int j = 0; j < 8; ++j) {
      const float* xr = xc + (size_t)s8[j] * 128;
      xlo[j] = xr[L];
      xhi[j] = xr[64 + L];
    }
#pragma unroll
    for (int j = 0; j < 8; ++j) {
      float sl0 = blo.x, sl1 = blo.y, sh0 = bhi.x, sh1 = bhi.y;
#pragma unroll
      for (int a = 0; a < ATTR; ++a) {
        sl0 = fmaf(eav[j][a], wlo[a].x, sl0);
        sl1 = fmaf(eav[j][a], wlo[a].y, sl1);
        sh0 = fmaf(eav[j][a], whi[a].x, sh0);
        sh1 = fmaf(eav[j][a], whi[a].y, sh1);
      }
      sl0 = fmaxf(sl0, 0.f); sl1 = fmaxf(sl1, 0.f);
      sh0 = fmaxf(sh0, 0.f); sh1 = fmaxf(sh1, 0.f);
      alo0 = fmaf(sl0, xlo[j], alo0);
      alo1 = fmaf(sl1, xlo[j], alo1);
      ahi0 = fmaf(sh0, xhi[j], ahi0);
      ahi1 = fmaf(sh1, xhi[j], ahi1);
    }
  }
  // ---- one group of 4 ----
  if (i0 + 4 <= end) {
    int s4[4];
#pragma unroll
    for (int j = 0; j < 4; ++j) s4[j] = srcs[i0 + j];
    float eav[4][ATTR];
#pragma unroll
    for (int j = 0; j < 4; ++j)
#pragma unroll
      for (int a = 0; a < ATTR; ++a) eav[j][a] = eas[(size_t)(i0 + j) * ATTR + a];
    float xlo[4], xhi[4];
#pragma unroll
    for (int j = 0; j < 4; ++j) {
      const float* xr = xc + (size_t)s4[j] * 128;
      xlo[j] = xr[L];
      xhi[j] = xr[64 + L];
    }
#pragma unroll
    for (int j = 0; j < 4; ++j) {
      float sl0 = blo.x, sl1 = blo.y, sh0 = bhi.x, sh1 = bhi.y;
#pragma unroll
      for (int a = 0; a < ATTR; ++a) {
        sl0 = fmaf(eav[j][a], wlo[a].x, sl0);
        sl1 = fmaf(eav[j][a], wlo[a].y, sl1);
        sh0 = fmaf(eav[j][a], whi[a].x, sh0);
        sh1 = fmaf(eav[j][a], whi[a].y, sh1);
      }
      sl0 = fmaxf(sl0, 0.f); sl1 = fmaxf(sl1, 0.f);
      sh0 = fmaxf(sh0, 0.f); sh1 = fmaxf(sh1, 0.f);
      alo0 = fmaf(sl0, xlo[j], alo0);
      alo1 = fmaf(sl1, xlo[j], alo1);
      ahi0 = fmaf(sh0, xhi[j], ahi0);
      ahi1 = fmaf(sh1, xhi[j], ahi1);
    }
    i0 += 4;
  }
  // ---- singles (<= 3) ----
  for (; i0 < end; ++i0) {
    const int s = srcs[i0];
    float eav[ATTR];
#pragma unroll
    for (int a = 0; a < ATTR; ++a) eav[a] = eas[(size_t)i0 * ATTR + a];
    const float* xr = xc + (size_t)s * 128;
    const float xl = xr[L];
    const float xh = xr[64 + L];
    float sl0 = blo.x, sl1 = blo.y, sh0 = bhi.x, sh1 = bhi.y;
#pragma unroll
    for (int a = 0; a < ATTR; ++a) {
      sl0 = fmaf(eav[a], wlo[a].x, sl0);
      sl1 = fmaf(eav[a], wlo[a].y, sl1);
      sh0 = fmaf(eav[a], whi[a].x, sh0);
      sh1 = fmaf(eav[a], whi[a].y, sh1);
    }
    sl0 = fmaxf(sl0, 0.f); sl1 = fmaxf(sl1, 0.f);
    sh0 = fmaxf(sh0, 0.f); sh1 = fmaxf(sh1, 0.f);
    alo0 = fmaf(sl0, xl, alo0);
    alo1 = fmaf(sl1, xl, alo1);
    ahi0 = fmaf(sh0, xh, ahi0);
    ahi1 = fmaf(sh1, xh, ahi1);
  }

  *(float2*)(aggr + (size_t)n * 256 + 2 * L)       = make_float2(alo0, alo1);
  *(float2*)(aggr + (size_t)n * 256 + 128 + 2 * L) = make_float2(ahi0, ahi1);
}

// ---------------- tier B: scatter (perm+srcs) + aggregate4 ----------------

__global__ __launch_bounds__(256) void scatter_kernel(
    const int* __restrict__ ei, int* __restrict__ cursors,
    int* __restrict__ perm, int* __restrict__ srcs, int E)
{
  int e = blockIdx.x * 256 + threadIdx.x;
  if (e < E) {
    int dst = ei[E + e];
    int slot = atomicAdd(&cursors[dst], 1);
    perm[slot] = e;
    srcs[slot] = ei[e];
  }
}

__global__ __launch_bounds__(256) void aggregate4_kernel(
    const float* __restrict__ x, const float* __restrict__ node_attr,
    const int* __restrict__ ei, const float* __restrict__ ea,
    const float* __restrict__ W_in, const float* __restrict__ b_in,
    const int* __restrict__ offsets, const int* __restrict__ perm,
    const int* __restrict__ srcs,
    float* __restrict__ aggr, int N)
{
  const int L = threadIdx.x & 63;
  const int n = __builtin_amdgcn_readfirstlane(blockIdx.x * 4 + (threadIdx.x >> 6));
  if (n >= N) return;

  float2 wlo[ATTR], whi[ATTR];
#pragma unroll
  for (int a = 0; a < ATTR; ++a) {
    wlo[a] = *(const float2*)(W_in + a * 256 + 2 * L);
    whi[a] = *(const float2*)(W_in + a * 256 + 128 + 2 * L);
  }
  const float2 blo = *(const float2*)(b_in + 2 * L);
  const float2 bhi = *(const float2*)(b_in + 128 + 2 * L);

  float alo0 = 0.f, alo1 = 0.f, ahi0 = 0.f, ahi1 = 0.f;
  const int beg = offsets[n], end = offsets[n + 1];

  for (int i0 = beg; i0 < end; i0 += 4) {
    const int cnt = end - i0;
    int e4[4], s4[4];
#pragma unroll
    for (int j = 0; j < 4; ++j) {
      const int idx = i0 + ((j < cnt) ? j : cnt - 1);
      e4[j] = perm[idx];
      s4[j] = srcs[idx];
    }
    float eav[4][ATTR];
#pragma unroll
    for (int j = 0; j < 4; ++j)
#pragma unroll
      for (int a = 0; a < ATTR; ++a) eav[j][a] = ea[(size_t)e4[j] * ATTR + a];
    float xlo[4], xhi[4];
#pragma unroll
    for (int j = 0; j < 4; ++j) {
      const float* xr = x + (size_t)s4[j] * 127;
      xlo[j] = xr[L];
      xhi[j] = (L == 63) ? node_attr[s4[j]] : xr[64 + L];
    }
#pragma unroll
    for (int j = 0; j < 4; ++j)
      if (j >= cnt) { xlo[j] = 0.f; xhi[j] = 0.f; }
#pragma unroll
    for (int j = 0; j < 4; ++j) {
      float sl0 = blo.x, sl1 = blo.y, sh0 = bhi.x, sh1 = bhi.y;
#pragma unroll
      for (int a = 0; a < ATTR; ++a) {
        sl0 = fmaf(eav[j][a], wlo[a].x, sl0);
        sl1 = fmaf(eav[j][a], wlo[a].y, sl1);
        sh0 = fmaf(eav[j][a], whi[a].x, sh0);
        sh1 = fmaf(eav[j][a], whi[a].y, sh1);
      }
      sl0 = fmaxf(sl0, 0.f); sl1 = fmaxf(sl1, 0.f);
      sh0 = fmaxf(sh0, 0.f); sh1 = fmaxf(sh1, 0.f);
      alo0 = fmaf(sl0, xlo[j], alo0);
      alo1 = fmaf(sl1, xlo[j], alo1);
      ahi0 = fmaf(sh0, xhi[j], ahi0);
      ahi1 = fmaf(sh1, xhi[j], ahi1);
    }
  }

  *(float2*)(aggr + (size_t)n * 256 + 2 * L)       = make_float2(alo0, alo1);
  *(float2*)(aggr + (size_t)n * 256 + 128 + 2 * L) = make_float2(ahi0, ahi1);
}

// ---------------- tier C: atomic edge kernel ----------------

__global__ __launch_bounds__(256) void edge_kernel(
    const float* __restrict__ x, const float* __restrict__ node_attr,
    const int* __restrict__ ei, const float* __restrict__ ea,
    const float* __restrict__ W_in, const float* __restrict__ b_in,
    float* __restrict__ aggr, int E, int N, int epw)
{
  const int lane = threadIdx.x & 63;
  const int wave = blockIdx.x * (blockDim.x >> 6) + (threadIdx.x >> 6);
  const int k0 = lane << 2;
  const int c0 = lane << 1;

  float w[ATTR][4];
#pragma unroll
  for (int a = 0; a < ATTR; ++a) {
    const float4 t = *(const float4*)(W_in + a * 256 + k0);
    w[a][0] = t.x; w[a][1] = t.y; w[a][2] = t.z; w[a][3] = t.w;
  }
  const float4 bt = *(const float4*)(b_in + k0);

  const long e0 = (long)wave * epw;
  for (int i = 0; i < epw; ++i) {
    const long e = e0 + i;
    if (e >= E) return;
    const int src = ei[e];
    const int dst = ei[E + e];

    float eav[ATTR];
#pragma unroll
    for (int a = 0; a < ATTR; ++a) eav[a] = ea[(size_t)e * ATTR + a];

    float s0 = bt.x, s1 = bt.y, s2 = bt.z, s3 = bt.w;
#pragma unroll
    for (int a = 0; a < ATTR; ++a) {
      s0 = fmaf(eav[a], w[a][0], s0);
      s1 = fmaf(eav[a], w[a][1], s1);
      s2 = fmaf(eav[a], w[a][2], s2);
      s3 = fmaf(eav[a], w[a][3], s3);
    }
    s0 = fmaxf(s0, 0.f); s1 = fmaxf(s1, 0.f);
    s2 = fmaxf(s2, 0.f); s3 = fmaxf(s3, 0.f);

    const float* xr = x + (size_t)src * 127;
    const float x0 = xr[c0];
    const float x1 = (lane == 63) ? node_attr[src] : xr[c0 + 1];

    float* ap = aggr + (size_t)dst * 256 + k0;
    atomicAdd(ap + 0, s0 * x0);
    atomicAdd(ap + 1, s1 * x0);
    atomicAdd(ap + 2, s2 * x1);
    atomicAdd(ap + 3, s3 * x1);
  }
}

// ---------------- D4: node GEMM + tanh ----------------

__global__ __launch_bounds__(256) void node_kernel2(
    const float* __restrict__ aggr, const float* __restrict__ W_out,
    const float* __restrict__ b_out, float* __restrict__ out, int N)
{
  __shared__ float Wl[64 * 128];   // 32 KB: k-chunk of W_out
  __shared__ float Al[64][68];     // 17 KB: 64 nodes x 64 ks (+4 pad)
  const int t = threadIdx.x;
  const int o4 = (t & 31) * 4;
  const int ng = t >> 5;
  const int nbase = blockIdx.x * 64;

  float acc[8][4];
#pragma unroll
  for (int j = 0; j < 8; ++j)
#pragma unroll
    for (int q = 0; q < 4; ++q) acc[j][q] = 0.f;

  for (int kc = 0; kc < 4; ++kc) {
    __syncthreads();
    const float4* wsrc = (const float4*)(W_out + kc * 64 * 128);
    float4* wdst = (float4*)Wl;
#pragma unroll
    for (int i = 0; i < 8; ++i) wdst[t + 256 * i] = wsrc[t + 256 * i];
    {
      const int r = t >> 2, q = t & 3;
      int row = nbase + r; if (row >= N) row = N - 1;
      const float4* asrc = (const float4*)(aggr + (size_t)row * 256 + kc * 64 + q * 16);
      float4 v0 = asrc[0], v1 = asrc[1], v2 = asrc[2], v3 = asrc[3];
      float4* adst = (float4*)&Al[r][q * 16];
      adst[0] = v0; adst[1] = v1; adst[2] = v2; adst[3] = v3;
    }
    __syncthreads();

    for (int k = 0; k < 64; k += 4) {
      float4 a4[8];
#pragma unroll
      for (int j = 0; j < 8; ++j) a4[j] = *(const float4*)&Al[ng * 8 + j][k];
#pragma unroll
      for (int kk = 0; kk < 4; ++kk) {
        const float4 w4 = *(const float4*)&Wl[(k + kk) * 128 + o4];
#pragma unroll
        for (int j = 0; j < 8; ++j) {
          const float av = (&a4[j].x)[kk];
          acc[j][0] = fmaf(av, w4.x, acc[j][0]);
          acc[j][1] = fmaf(av, w4.y, acc[j][1]);
          acc[j][2] = fmaf(av, w4.z, acc[j][2]);
          acc[j][3] = fmaf(av, w4.w, acc[j][3]);
        }
      }
    }
  }

  const float4 b4 = *(const float4*)(b_out + o4);
#pragma unroll
  for (int j = 0; j < 8; ++j) {
    const int n = nbase + ng * 8 + j;
    if (n < N) {
      float4 r;
      r.x = tanhf(acc[j][0] + b4.x);
      r.y = tanhf(acc[j][1] + b4.y);
      r.z = tanhf(acc[j][2] + b4.z);
      r.w = tanhf(acc[j][3] + b4.w);
      *(float4*)(out + (size_t)n * 128 + o4) = r;
    }
  }
}

// ---------------- launch ----------------

extern "C" void kernel_launch(void* const* d_in, const int* in_sizes, int n_in,
                              void* d_out, int out_size, void* d_ws, size_t ws_size,
                              hipStream_t stream) {
  const float* x         = (const float*)d_in[0];
  const float* node_attr = (const float*)d_in[1];
  const int*   ei        = (const int*)d_in[2];
  const float* ea        = (const float*)d_in[3];
  const float* W_in      = (const float*)d_in[4];
  const float* b_in      = (const float*)d_in[5];
  const float* W_out     = (const float*)d_in[6];
  const float* b_out     = (const float*)d_in[7];
  float* out = (float*)d_out;

  const int N = in_sizes[0] / 127;   // 100000
  const int E = in_sizes[2] / 2;     // 1600000

  auto align16 = [](size_t v) { return (v + 15) & ~(size_t)15; };
  const size_t szCounts  = align16((size_t)N * 4);
  const size_t szDone    = 16;
  const size_t szOffsets = align16(((size_t)N + 1) * 4);
  const size_t szCursors = align16((size_t)N * 4);
  const size_t szPerm    = align16((size_t)E * 4);
  const size_t szSrcs    = align16((size_t)E * 4);
  const size_t szEas     = align16((size_t)E * ATTR * 4);
  const size_t szXc      = align16((size_t)N * 128 * 4);
  const size_t szAggr    = (size_t)N * 256 * 4;

  const size_t needA = szCounts + szDone + szOffsets + szCursors +
                       szSrcs + szEas + szXc + szAggr;            // ~199 MB
  const size_t needB = szCounts + szDone + szOffsets + szCursors +
                       szPerm + szSrcs + szAggr;                  // ~117 MB

  const int nodeBlocks = (N + 63) / 64;
  const int histBlocks = (E + 1023) / 1024;
  const int SB = (E + 255) / 256;                 // scatter blocks
  const int CB = (N * 32 + 255) / 256;            // concat blocks

  if (ws_size >= needA) {
    char* p = (char*)d_ws;
    int* counts   = (int*)p;     p += szCounts;
    int* done     = (int*)p;     p += szDone;
    int* offsets  = (int*)p;     p += szOffsets;
    int* cursors  = (int*)p;     p += szCursors;
    int* srcs     = (int*)p;     p += szSrcs;
    float* eas    = (float*)p;   p += szEas;
    float* xc     = (float*)p;   p += szXc;
    float* aggr   = (float*)p;

    hipMemsetAsync(counts, 0, szCounts + szDone, stream);
    hist_scan_kernel<<<histBlocks, 256, 0, stream>>>(
        ei, counts, done, offsets, cursors, E, N);
    scatter_concat_kernel<<<SB + CB, 256, 0, stream>>>(
        ei, ea, cursors, srcs, eas, x, node_attr, xc, E, N, SB);
    aggregate8b_kernel<<<(N + 3) / 4, 256, 0, stream>>>(
        xc, W_in, b_in, offsets, srcs, eas, aggr, N);
    node_kernel2<<<nodeBlocks, 256, 0, stream>>>(aggr, W_out, b_out, out, N);
  } else if (ws_size >= needB) {
    char* p = (char*)d_ws;
    int* counts   = (int*)p;     p += szCounts;
    int* done     = (int*)p;     p += szDone;
    int* offsets  = (int*)p;     p += szOffsets;
    int* cursors  = (int*)p;     p += szCursors;
    int* perm     = (int*)p;     p += szPerm;
    int* srcs     = (int*)p;     p += szSrcs;
    float* aggr   = (float*)p;

    hipMemsetAsync(counts, 0, szCounts + szDone, stream);
    hist_scan_kernel<<<histBlocks, 256, 0, stream>>>(
        ei, counts, done, offsets, cursors, E, N);
    scatter_kernel<<<SB, 256, 0, stream>>>(ei, cursors, perm, srcs, E);
    aggregate4_kernel<<<(N + 3) / 4, 256, 0, stream>>>(
        x, node_attr, ei, ea, W_in, b_in, offsets, perm, srcs, aggr, N);
    node_kernel2<<<nodeBlocks, 256, 0, stream>>>(aggr, W_out, b_out, out, N);
  } else {
    float* aggr = (float*)d_ws;
    hipMemsetAsync(aggr, 0, (size_t)N * 256 * 4, stream);
    const int EPW = 4;
    const int waves = (E + EPW - 1) / EPW;
    edge_kernel<<<(waves + 3) / 4, 256, 0, stream>>>(
        x, node_attr, ei, ea, W_in, b_in, aggr, E, N, EPW);
    node_kernel2<<<nodeBlocks, 256, 0, stream>>>(aggr, W_out, b_out, out, N);
  }
}

// Round 7
// 560.186 us; speedup vs baseline: 1.3409x; 1.3409x over previous
//
#include <hip/hip_runtime.h>

// GNetFVnewGCN: x[N,127], node_attr[N,1], edge_index[2,E] (int32), edge_attr[E,6],
// W_in[6,256], b_in[256], W_out[256,128], b_out[128] -> out[N,128] fp32
//
// R7: R6's single-block double-read scan caused replay-nondeterministic
// corruption (pass-1/pass-2 reads of atomic-written counts can disagree).
// Reverted to the R4-proven single-read scan shape, compressed to 2 dispatches:
//   D0 memset(counts)
//   D1 hist          : histogram of dst (int4 loads)
//   D2 scan1         : per-block exclusive offsets + block sums (reads counts ONCE)
//   D3 scanB         : per-block redundant bsum reduce -> add base, write cursors
//   D4 scatter_concat: payload scatter (srcs+eas) || xc concat   [R5-validated]
//   D5 aggregate8b   : atomic-free wave/node aggregation, 8/4/1 tail-split
//   D6 node_kernel2  : fp32 GEMM [N,256]@[256,128] + tanh
// Tiers: A (payload ~199MB) -> B (perm path ~117MB) -> C (atomic).

#define ATTR 6
#define SCAN_CHUNK 1024

// ---------------- D1: histogram ----------------

__global__ __launch_bounds__(256) void hist_kernel(
    const int* __restrict__ ei, int* __restrict__ counts, int E)
{
  const int e0 = blockIdx.x * 1024 + threadIdx.x * 4;
  if (((E & 3) == 0) && (e0 + 4 <= E)) {
    const int4 d = *(const int4*)(ei + E + e0);
    atomicAdd(&counts[d.x], 1);
    atomicAdd(&counts[d.y], 1);
    atomicAdd(&counts[d.z], 1);
    atomicAdd(&counts[d.w], 1);
  } else {
#pragma unroll
    for (int j = 0; j < 4; ++j) {
      const int e = e0 + j;
      if (e < E) atomicAdd(&counts[ei[E + e]], 1);
    }
  }
}

// ---------------- D2: per-block exclusive scan (reads counts exactly once) ----

__global__ __launch_bounds__(256) void scan1_kernel(
    const int* __restrict__ counts, int* __restrict__ offsets,
    int* __restrict__ bsum, int N)
{
  __shared__ int sdata[256];
  const int t = threadIdx.x;
  const int base = blockIdx.x * SCAN_CHUNK + t * 4;
  int c[4]; int s = 0;
#pragma unroll
  for (int j = 0; j < 4; ++j) { int i = base + j; c[j] = (i < N) ? counts[i] : 0; s += c[j]; }
  sdata[t] = s;
  __syncthreads();
  for (int d = 1; d < 256; d <<= 1) {
    int tv = (t >= d) ? sdata[t - d] : 0;
    __syncthreads();
    sdata[t] += tv;
    __syncthreads();
  }
  int excl = sdata[t] - s;   // exclusive prefix of this thread within block
#pragma unroll
  for (int j = 0; j < 4; ++j) { int i = base + j; if (i < N) offsets[i] = excl; excl += c[j]; }
  if (t == 255) bsum[blockIdx.x] = sdata[255];
}

// ---------------- D3: add block bases (redundant per-block bsum reduce) -------

__global__ __launch_bounds__(256) void scanB_kernel(
    int* __restrict__ offsets, int* __restrict__ cursors,
    const int* __restrict__ bsum, int N, int E)
{
  __shared__ int red[4];
  const int t = threadIdx.x;
  // sum of bsum[0 .. blockIdx.x): strided load + wave reduce + LDS combine
  int v = 0;
  for (int k = t; k < (int)blockIdx.x; k += 256) v += bsum[k];
#pragma unroll
  for (int d = 32; d > 0; d >>= 1) v += __shfl_down(v, d, 64);
  if ((t & 63) == 0) red[t >> 6] = v;
  __syncthreads();
  const int add = red[0] + red[1] + red[2] + red[3];

  const int base = blockIdx.x * SCAN_CHUNK + t * 4;
#pragma unroll
  for (int j = 0; j < 4; ++j) {
    const int i = base + j;
    if (i < N) { const int o = offsets[i] + add; offsets[i] = o; cursors[i] = o; }
  }
  if (blockIdx.x == 0 && t == 0) offsets[N] = E;
}

// ---------------- D4: payload scatter || concat, fused ----------------

__global__ __launch_bounds__(256) void scatter_concat_kernel(
    const int* __restrict__ ei, const float* __restrict__ ea,
    int* __restrict__ cursors, int* __restrict__ srcs, float* __restrict__ eas,
    const float* __restrict__ x, const float* __restrict__ na,
    float* __restrict__ xc, int E, int N, int SB)
{
  if ((int)blockIdx.x < SB) {
    const int e = blockIdx.x * 256 + threadIdx.x;
    if (e < E) {
      const int dst = ei[E + e];
      const int slot = atomicAdd(&cursors[dst], 1);
      srcs[slot] = ei[e];
      const float2 a0 = *(const float2*)(ea + (size_t)e * ATTR + 0);
      const float2 a1 = *(const float2*)(ea + (size_t)e * ATTR + 2);
      const float2 a2 = *(const float2*)(ea + (size_t)e * ATTR + 4);
      float* ep = eas + (size_t)slot * ATTR;
      *(float2*)(ep + 0) = a0;
      *(float2*)(ep + 2) = a1;
      *(float2*)(ep + 4) = a2;
    }
  } else {
    const int gid = (blockIdx.x - SB) * 256 + threadIdx.x;  // thread per float4
    const int row = gid >> 5;
    const int c4 = (gid & 31) * 4;
    if (row < N) {
      const float* xr = x + (size_t)row * 127;
      float4 v;
      v.x = xr[c4];
      v.y = xr[c4 + 1];
      v.z = xr[c4 + 2];
      v.w = (c4 == 124) ? na[row] : xr[c4 + 3];
      *(float4*)(xc + (size_t)row * 128 + c4) = v;
    }
  }
}

// ---------------- D5: aggregation, wave/node, 8/4/1 tail-split ----------------

__global__ __launch_bounds__(256) void aggregate8b_kernel(
    const float* __restrict__ xc,
    const float* __restrict__ W_in, const float* __restrict__ b_in,
    const int* __restrict__ offsets, const int* __restrict__ srcs,
    const float* __restrict__ eas,
    float* __restrict__ aggr, int N)
{
  const int L = threadIdx.x & 63;
  const int n = __builtin_amdgcn_readfirstlane(blockIdx.x * 4 + (threadIdx.x >> 6));
  if (n >= N) return;

  // lane L owns channels c_lo=L (k=2L,2L+1) and c_hi=64+L (k=128+2L,129+2L)
  float2 wlo[ATTR], whi[ATTR];
#pragma unroll
  for (int a = 0; a < ATTR; ++a) {
    wlo[a] = *(const float2*)(W_in + a * 256 + 2 * L);
    whi[a] = *(const float2*)(W_in + a * 256 + 128 + 2 * L);
  }
  const float2 blo = *(const float2*)(b_in + 2 * L);
  const float2 bhi = *(const float2*)(b_in + 128 + 2 * L);

  float alo0 = 0.f, alo1 = 0.f, ahi0 = 0.f, ahi1 = 0.f;
  const int beg = __builtin_amdgcn_readfirstlane(offsets[n]);
  const int end = __builtin_amdgcn_readfirstlane(offsets[n + 1]);

  int i0 = beg;
  // ---- full groups of 8, no clamps ----
  for (; i0 + 8 <= end; i0 += 8) {
    int s8[8];
#pragma unroll
    for (int j = 0; j < 8; ++j) s8[j] = srcs[i0 + j];
    float eav[8][ATTR];
#pragma unroll
    for (int j = 0; j < 8; ++j)
#pragma unroll
      for (int a = 0; a < ATTR; ++a) eav[j][a] = eas[(size_t)(i0 + j) * ATTR + a];

    float xlo[8], xhi[8];
#pragma unroll
    for (int j = 0; j < 8; ++j) {
      const float* xr = xc + (size_t)s8[j] * 128;
      xlo[j] = xr[L];
      xhi[j] = xr[64 + L];
    }
#pragma unroll
    for (int j = 0; j < 8; ++j) {
      float sl0 = blo.x, sl1 = blo.y, sh0 = bhi.x, sh1 = bhi.y;
#pragma unroll
      for (int a = 0; a < ATTR; ++a) {
        sl0 = fmaf(eav[j][a], wlo[a].x, sl0);
        sl1 = fmaf(eav[j][a], wlo[a].y, sl1);
        sh0 = fmaf(eav[j][a], whi[a].x, sh0);
        sh1 = fmaf(eav[j][a], whi[a].y, sh1);
      }
      sl0 = fmaxf(sl0, 0.f); sl1 = fmaxf(sl1, 0.f);
      sh0 = fmaxf(sh0, 0.f); sh1 = fmaxf(sh1, 0.f);
      alo0 = fmaf(sl0, xlo[j], alo0);
      alo1 = fmaf(sl1, xlo[j], alo1);
      ahi0 = fmaf(sh0, xhi[j], ahi0);
      ahi1 = fmaf(sh1, xhi[j], ahi1);
    }
  }
  // ---- one group of 4 ----
  if (i0 + 4 <= end) {
    int s4[4];
#pragma unroll
    for (int j = 0; j < 4; ++j) s4[j] = srcs[i0 + j];
    float eav[4][ATTR];
#pragma unroll
    for (int j = 0; j < 4; ++j)
#pragma unroll
      for (int a = 0; a < ATTR; ++a) eav[j][a] = eas[(size_t)(i0 + j) * ATTR + a];
    float xlo[4], xhi[4];
#pragma unroll
    for (int j = 0; j < 4; ++j) {
      const float* xr = xc + (size_t)s4[j] * 128;
      xlo[j] = xr[L];
      xhi[j] = xr[64 + L];
    }
#pragma unroll
    for (int j = 0; j < 4; ++j) {
      float sl0 = blo.x, sl1 = blo.y, sh0 = bhi.x, sh1 = bhi.y;
#pragma unroll
      for (int a = 0; a < ATTR; ++a) {
        sl0 = fmaf(eav[j][a], wlo[a].x, sl0);
        sl1 = fmaf(eav[j][a], wlo[a].y, sl1);
        sh0 = fmaf(eav[j][a], whi[a].x, sh0);
        sh1 = fmaf(eav[j][a], whi[a].y, sh1);
      }
      sl0 = fmaxf(sl0, 0.f); sl1 = fmaxf(sl1, 0.f);
      sh0 = fmaxf(sh0, 0.f); sh1 = fmaxf(sh1, 0.f);
      alo0 = fmaf(sl0, xlo[j], alo0);
      alo1 = fmaf(sl1, xlo[j], alo1);
      ahi0 = fmaf(sh0, xhi[j], ahi0);
      ahi1 = fmaf(sh1, xhi[j], ahi1);
    }
    i0 += 4;
  }
  // ---- singles (<= 3) ----
  for (; i0 < end; ++i0) {
    const int s = srcs[i0];
    float eav[ATTR];
#pragma unroll
    for (int a = 0; a < ATTR; ++a) eav[a] = eas[(size_t)i0 * ATTR + a];
    const float* xr = xc + (size_t)s * 128;
    const float xl = xr[L];
    const float xh = xr[64 + L];
    float sl0 = blo.x, sl1 = blo.y, sh0 = bhi.x, sh1 = bhi.y;
#pragma unroll
    for (int a = 0; a < ATTR; ++a) {
      sl0 = fmaf(eav[a], wlo[a].x, sl0);
      sl1 = fmaf(eav[a], wlo[a].y, sl1);
      sh0 = fmaf(eav[a], whi[a].x, sh0);
      sh1 = fmaf(eav[a], whi[a].y, sh1);
    }
    sl0 = fmaxf(sl0, 0.f); sl1 = fmaxf(sl1, 0.f);
    sh0 = fmaxf(sh0, 0.f); sh1 = fmaxf(sh1, 0.f);
    alo0 = fmaf(sl0, xl, alo0);
    alo1 = fmaf(sl1, xl, alo1);
    ahi0 = fmaf(sh0, xh, ahi0);
    ahi1 = fmaf(sh1, xh, ahi1);
  }

  *(float2*)(aggr + (size_t)n * 256 + 2 * L)       = make_float2(alo0, alo1);
  *(float2*)(aggr + (size_t)n * 256 + 128 + 2 * L) = make_float2(ahi0, ahi1);
}

// ---------------- tier B: scatter (perm+srcs) + aggregate4 ----------------

__global__ __launch_bounds__(256) void scatter_kernel(
    const int* __restrict__ ei, int* __restrict__ cursors,
    int* __restrict__ perm, int* __restrict__ srcs, int E)
{
  int e = blockIdx.x * 256 + threadIdx.x;
  if (e < E) {
    int dst = ei[E + e];
    int slot = atomicAdd(&cursors[dst], 1);
    perm[slot] = e;
    srcs[slot] = ei[e];
  }
}

__global__ __launch_bounds__(256) void aggregate4_kernel(
    const float* __restrict__ x, const float* __restrict__ node_attr,
    const int* __restrict__ ei, const float* __restrict__ ea,
    const float* __restrict__ W_in, const float* __restrict__ b_in,
    const int* __restrict__ offsets, const int* __restrict__ perm,
    const int* __restrict__ srcs,
    float* __restrict__ aggr, int N)
{
  const int L = threadIdx.x & 63;
  const int n = __builtin_amdgcn_readfirstlane(blockIdx.x * 4 + (threadIdx.x >> 6));
  if (n >= N) return;

  float2 wlo[ATTR], whi[ATTR];
#pragma unroll
  for (int a = 0; a < ATTR; ++a) {
    wlo[a] = *(const float2*)(W_in + a * 256 + 2 * L);
    whi[a] = *(const float2*)(W_in + a * 256 + 128 + 2 * L);
  }
  const float2 blo = *(const float2*)(b_in + 2 * L);
  const float2 bhi = *(const float2*)(b_in + 128 + 2 * L);

  float alo0 = 0.f, alo1 = 0.f, ahi0 = 0.f, ahi1 = 0.f;
  const int beg = offsets[n], end = offsets[n + 1];

  for (int i0 = beg; i0 < end; i0 += 4) {
    const int cnt = end - i0;
    int e4[4], s4[4];
#pragma unroll
    for (int j = 0; j < 4; ++j) {
      const int idx = i0 + ((j < cnt) ? j : cnt - 1);
      e4[j] = perm[idx];
      s4[j] = srcs[idx];
    }
    float eav[4][ATTR];
#pragma unroll
    for (int j = 0; j < 4; ++j)
#pragma unroll
      for (int a = 0; a < ATTR; ++a) eav[j][a] = ea[(size_t)e4[j] * ATTR + a];
    float xlo[4], xhi[4];
#pragma unroll
    for (int j = 0; j < 4; ++j) {
      const float* xr = x + (size_t)s4[j] * 127;
      xlo[j] = xr[L];
      xhi[j] = (L == 63) ? node_attr[s4[j]] : xr[64 + L];
    }
#pragma unroll
    for (int j = 0; j < 4; ++j)
      if (j >= cnt) { xlo[j] = 0.f; xhi[j] = 0.f; }
#pragma unroll
    for (int j = 0; j < 4; ++j) {
      float sl0 = blo.x, sl1 = blo.y, sh0 = bhi.x, sh1 = bhi.y;
#pragma unroll
      for (int a = 0; a < ATTR; ++a) {
        sl0 = fmaf(eav[j][a], wlo[a].x, sl0);
        sl1 = fmaf(eav[j][a], wlo[a].y, sl1);
        sh0 = fmaf(eav[j][a], whi[a].x, sh0);
        sh1 = fmaf(eav[j][a], whi[a].y, sh1);
      }
      sl0 = fmaxf(sl0, 0.f); sl1 = fmaxf(sl1, 0.f);
      sh0 = fmaxf(sh0, 0.f); sh1 = fmaxf(sh1, 0.f);
      alo0 = fmaf(sl0, xlo[j], alo0);
      alo1 = fmaf(sl1, xlo[j], alo1);
      ahi0 = fmaf(sh0, xhi[j], ahi0);
      ahi1 = fmaf(sh1, xhi[j], ahi1);
    }
  }

  *(float2*)(aggr + (size_t)n * 256 + 2 * L)       = make_float2(alo0, alo1);
  *(float2*)(aggr + (size_t)n * 256 + 128 + 2 * L) = make_float2(ahi0, ahi1);
}

// ---------------- tier C: atomic edge kernel ----------------

__global__ __launch_bounds__(256) void edge_kernel(
    const float* __restrict__ x, const float* __restrict__ node_attr,
    const int* __restrict__ ei, const float* __restrict__ ea,
    const float* __restrict__ W_in, const float* __restrict__ b_in,
    float* __restrict__ aggr, int E, int N, int epw)
{
  const int lane = threadIdx.x & 63;
  const int wave = blockIdx.x * (blockDim.x >> 6) + (threadIdx.x >> 6);
  const int k0 = lane << 2;
  const int c0 = lane << 1;

  float w[ATTR][4];
#pragma unroll
  for (int a = 0; a < ATTR; ++a) {
    const float4 t = *(const float4*)(W_in + a * 256 + k0);
    w[a][0] = t.x; w[a][1] = t.y; w[a][2] = t.z; w[a][3] = t.w;
  }
  const float4 bt = *(const float4*)(b_in + k0);

  const long e0 = (long)wave * epw;
  for (int i = 0; i < epw; ++i) {
    const long e = e0 + i;
    if (e >= E) return;
    const int src = ei[e];
    const int dst = ei[E + e];

    float eav[ATTR];
#pragma unroll
    for (int a = 0; a < ATTR; ++a) eav[a] = ea[(size_t)e * ATTR + a];

    float s0 = bt.x, s1 = bt.y, s2 = bt.z, s3 = bt.w;
#pragma unroll
    for (int a = 0; a < ATTR; ++a) {
      s0 = fmaf(eav[a], w[a][0], s0);
      s1 = fmaf(eav[a], w[a][1], s1);
      s2 = fmaf(eav[a], w[a][2], s2);
      s3 = fmaf(eav[a], w[a][3], s3);
    }
    s0 = fmaxf(s0, 0.f); s1 = fmaxf(s1, 0.f);
    s2 = fmaxf(s2, 0.f); s3 = fmaxf(s3, 0.f);

    const float* xr = x + (size_t)src * 127;
    const float x0 = xr[c0];
    const float x1 = (lane == 63) ? node_attr[src] : xr[c0 + 1];

    float* ap = aggr + (size_t)dst * 256 + k0;
    atomicAdd(ap + 0, s0 * x0);
    atomicAdd(ap + 1, s1 * x0);
    atomicAdd(ap + 2, s2 * x1);
    atomicAdd(ap + 3, s3 * x1);
  }
}

// ---------------- D6: node GEMM + tanh ----------------

__global__ __launch_bounds__(256) void node_kernel2(
    const float* __restrict__ aggr, const float* __restrict__ W_out,
    const float* __restrict__ b_out, float* __restrict__ out, int N)
{
  __shared__ float Wl[64 * 128];   // 32 KB: k-chunk of W_out
  __shared__ float Al[64][68];     // 17 KB: 64 nodes x 64 ks (+4 pad)
  const int t = threadIdx.x;
  const int o4 = (t & 31) * 4;
  const int ng = t >> 5;
  const int nbase = blockIdx.x * 64;

  float acc[8][4];
#pragma unroll
  for (int j = 0; j < 8; ++j)
#pragma unroll
    for (int q = 0; q < 4; ++q) acc[j][q] = 0.f;

  for (int kc = 0; kc < 4; ++kc) {
    __syncthreads();
    const float4* wsrc = (const float4*)(W_out + kc * 64 * 128);
    float4* wdst = (float4*)Wl;
#pragma unroll
    for (int i = 0; i < 8; ++i) wdst[t + 256 * i] = wsrc[t + 256 * i];
    {
      const int r = t >> 2, q = t & 3;
      int row = nbase + r; if (row >= N) row = N - 1;
      const float4* asrc = (const float4*)(aggr + (size_t)row * 256 + kc * 64 + q * 16);
      float4 v0 = asrc[0], v1 = asrc[1], v2 = asrc[2], v3 = asrc[3];
      float4* adst = (float4*)&Al[r][q * 16];
      adst[0] = v0; adst[1] = v1; adst[2] = v2; adst[3] = v3;
    }
    __syncthreads();

    for (int k = 0; k < 64; k += 4) {
      float4 a4[8];
#pragma unroll
      for (int j = 0; j < 8; ++j) a4[j] = *(const float4*)&Al[ng * 8 + j][k];
#pragma unroll
      for (int kk = 0; kk < 4; ++kk) {
        const float4 w4 = *(const float4*)&Wl[(k + kk) * 128 + o4];
#pragma unroll
        for (int j = 0; j < 8; ++j) {
          const float av = (&a4[j].x)[kk];
          acc[j][0] = fmaf(av, w4.x, acc[j][0]);
          acc[j][1] = fmaf(av, w4.y, acc[j][1]);
          acc[j][2] = fmaf(av, w4.z, acc[j][2]);
          acc[j][3] = fmaf(av, w4.w, acc[j][3]);
        }
      }
    }
  }

  const float4 b4 = *(const float4*)(b_out + o4);
#pragma unroll
  for (int j = 0; j < 8; ++j) {
    const int n = nbase + ng * 8 + j;
    if (n < N) {
      float4 r;
      r.x = tanhf(acc[j][0] + b4.x);
      r.y = tanhf(acc[j][1] + b4.y);
      r.z = tanhf(acc[j][2] + b4.z);
      r.w = tanhf(acc[j][3] + b4.w);
      *(float4*)(out + (size_t)n * 128 + o4) = r;
    }
  }
}

// ---------------- launch ----------------

extern "C" void kernel_launch(void* const* d_in, const int* in_sizes, int n_in,
                              void* d_out, int out_size, void* d_ws, size_t ws_size,
                              hipStream_t stream) {
  const float* x         = (const float*)d_in[0];
  const float* node_attr = (const float*)d_in[1];
  const int*   ei        = (const int*)d_in[2];
  const float* ea        = (const float*)d_in[3];
  const float* W_in      = (const float*)d_in[4];
  const float* b_in      = (const float*)d_in[5];
  const float* W_out     = (const float*)d_in[6];
  const float* b_out     = (const float*)d_in[7];
  float* out = (float*)d_out;

  const int N = in_sizes[0] / 127;   // 100000
  const int E = in_sizes[2] / 2;     // 1600000

  auto align16 = [](size_t v) { return (v + 15) & ~(size_t)15; };
  const size_t szCounts  = align16((size_t)N * 4);
  const size_t szOffsets = align16(((size_t)N + 1) * 4);
  const size_t szCursors = align16((size_t)N * 4);
  const size_t szBsum    = align16(((size_t)N / SCAN_CHUNK + 2) * 4);
  const size_t szPerm    = align16((size_t)E * 4);
  const size_t szSrcs    = align16((size_t)E * 4);
  const size_t szEas     = align16((size_t)E * ATTR * 4);
  const size_t szXc      = align16((size_t)N * 128 * 4);
  const size_t szAggr    = (size_t)N * 256 * 4;

  const size_t needA = szCounts + szOffsets + szCursors + szBsum +
                       szSrcs + szEas + szXc + szAggr;            // ~199 MB
  const size_t needB = szCounts + szOffsets + szCursors + szBsum +
                       szPerm + szSrcs + szAggr;                  // ~117 MB

  const int nodeBlocks = (N + 63) / 64;
  const int histBlocks = (E + 1023) / 1024;
  const int nb = (N + SCAN_CHUNK - 1) / SCAN_CHUNK;   // 98
  const int SB = (E + 255) / 256;                     // scatter blocks
  const int CB = (N * 32 + 255) / 256;                // concat blocks

  if (ws_size >= needA) {
    char* p = (char*)d_ws;
    int* counts   = (int*)p;     p += szCounts;
    int* offsets  = (int*)p;     p += szOffsets;
    int* cursors  = (int*)p;     p += szCursors;
    int* bsum     = (int*)p;     p += szBsum;
    int* srcs     = (int*)p;     p += szSrcs;
    float* eas    = (float*)p;   p += szEas;
    float* xc     = (float*)p;   p += szXc;
    float* aggr   = (float*)p;

    hipMemsetAsync(counts, 0, szCounts, stream);
    hist_kernel<<<histBlocks, 256, 0, stream>>>(ei, counts, E);
    scan1_kernel<<<nb, 256, 0, stream>>>(counts, offsets, bsum, N);
    scanB_kernel<<<nb, 256, 0, stream>>>(offsets, cursors, bsum, N, E);
    scatter_concat_kernel<<<SB + CB, 256, 0, stream>>>(
        ei, ea, cursors, srcs, eas, x, node_attr, xc, E, N, SB);
    aggregate8b_kernel<<<(N + 3) / 4, 256, 0, stream>>>(
        xc, W_in, b_in, offsets, srcs, eas, aggr, N);
    node_kernel2<<<nodeBlocks, 256, 0, stream>>>(aggr, W_out, b_out, out, N);
  } else if (ws_size >= needB) {
    char* p = (char*)d_ws;
    int* counts   = (int*)p;     p += szCounts;
    int* offsets  = (int*)p;     p += szOffsets;
    int* cursors  = (int*)p;     p += szCursors;
    int* bsum     = (int*)p;     p += szBsum;
    int* perm     = (int*)p;     p += szPerm;
    int* srcs     = (int*)p;     p += szSrcs;
    float* aggr   = (float*)p;

    hipMemsetAsync(counts, 0, szCounts, stream);
    hist_kernel<<<histBlocks, 256, 0, stream>>>(ei, counts, E);
    scan1_kernel<<<nb, 256, 0, stream>>>(counts, offsets, bsum, N);
    scanB_kernel<<<nb, 256, 0, stream>>>(offsets, cursors, bsum, N, E);
    scatter_kernel<<<SB, 256, 0, stream>>>(ei, cursors, perm, srcs, E);
    aggregate4_kernel<<<(N + 3) / 4, 256, 0, stream>>>(
        x, node_attr, ei, ea, W_in, b_in, offsets, perm, srcs, aggr, N);
    node_kernel2<<<nodeBlocks, 256, 0, stream>>>(aggr, W_out, b_out, out, N);
  } else {
    float* aggr = (float*)d_ws;
    hipMemsetAsync(aggr, 0, (size_t)N * 256 * 4, stream);
    const int EPW = 4;
    const int waves = (E + EPW - 1) / EPW;
    edge_kernel<<<(waves + 3) / 4, 256, 0, stream>>>(
        x, node_attr, ei, ea, W_in, b_in, aggr, E, N, EPW);
    node_kernel2<<<nodeBlocks, 256, 0, stream>>>(aggr, W_out, b_out, out, N);
  }
}